// Round 9
// baseline (7349.818 us; speedup 1.0000x reference)
//
#include <hip/hip_runtime.h>
#include <math.h>

#define TT 1024
#define BB 64
#define II 128
#define HH 256
#define OO 128
#define GPB 16           // blocks (members) per group
#define ZPAD 400         // per-wave z strip stride (floats), 16B-aligned

// ws layout: flags 256 blocks x 16 ints (64B/block) = 16KB @0; abort @int 4096
// (byte 16384); hbuf [2][64][256] floats @float 8192 (byte 32768)
#define WS_HBUF_F 8192
#define WS_CLEAR_B 20480

__device__ __forceinline__ float rcp(float v) { return __builtin_amdgcn_rcpf(v); }
__device__ __forceinline__ float sigm(float v) { return rcp(1.f + __expf(-v)); }
__device__ __forceinline__ float ftanh(float v) {
    return __builtin_fmaf(-2.f, rcp(__expf(2.f * v) + 1.f), 1.f);
}

// Each wave owns ONE batch; each lane owns ONE gate column (384-row dot).
// Weights live entirely in VGPRs (96 x float4 = 384 regs). No barriers in loop.
extern "C" __global__ void __launch_bounds__(256, 1) lstm_scan(
    const float* __restrict__ x, const float* __restrict__ W,
    const float* __restrict__ U, const float* __restrict__ bias,
    float* __restrict__ wsf)
{
    __shared__ float z[4 * ZPAD];         // per-wave private strips

    int*   flags  = (int*)wsf;            // [block][wave] flag: block*16 + w*4
    int*   abortp = ((int*)wsf) + 4096;
    float* hbuf   = wsf + WS_HBUF_F;      // [2][64][256]

    const int tid  = threadIdx.x;
    const int gid  = blockIdx.x & 15;     // group
    const int p    = blockIdx.x >> 4;     // member: owns h-indices [16p,16p+16)
    const int lane = tid & 63;
    const int w    = tid >> 6;            // wave == batch slot in group
    const int myb  = 4 * gid + w;         // this wave's batch
    const int j    = lane & 15;

    // this lane's logical column = lane; global gate column:
    const int gcol = (lane >> 4) * HH + p * 16 + j;

    // ---- weights in VGPRs: wr[k] = rows 4k..4k+3 of [W;U] at column gcol
    float4 wr[96];
#pragma unroll
    for (int k = 0; k < 96; ++k) {
        const float* base = (k < 32)
            ? (W + (size_t)(4 * k) * 1024 + gcol)
            : (U + (size_t)(4 * k - 128) * 1024 + gcol);
        wr[k].x = base[0];
        wr[k].y = base[1024];
        wr[k].z = base[2048];
        wr[k].w = base[3072];
    }
    const float bia_reg = bias[gcol];
    float creg = 0.f;                     // c-state lives in lanes 0..15

    float* zw = z + w * ZPAD;
    // zero h-part of this wave's strip; stage x_1
    for (int i = lane; i < HH; i += 64) zw[II + i] = 0.f;
    float4 xv = make_float4(0.f, 0.f, 0.f, 0.f);
    if (lane < 32) {
        xv = *(const float4*)(x + (size_t)myb * TT * II + 4 * lane);
        *(float4*)(zw + 4 * lane) = xv;
    }
    // no barrier: strip is private to this wave; lgkmcnt orders within-wave

    int ab = 0;
    for (int t = 1; t <= TT; ++t) {
        float acc[4] = {0.f, 0.f, 0.f, 0.f};

        // ---- x-dot (rows 0..127), h-independent, before the wait
#pragma unroll
        for (int k = 0; k < 32; ++k) {
            const float4 zv = *(const float4*)(zw + 4 * k);
            acc[k & 3] += zv.x * wr[k].x + zv.y * wr[k].y
                        + zv.z * wr[k].z + zv.w * wr[k].w;
        }

        // ---- issue x_{t+1} load early (latency hides under poll + h-dot)
        if (t < TT && lane < 32)
            xv = *(const float4*)(x + ((size_t)myb * TT + t) * II + 4 * lane);

        // ---- per-wave: poll 16 member flags for THIS batch slot, then pull h
        if (t > 1) {
            const int need = t - 1;
            const int* fp = &flags[((lane & 15) * GPB + gid) * 16 + w * 4];
            int it = 0;
            for (;;) {
                int f1 = need, f2 = need;
                if (lane < GPB) {
                    f1 = __hip_atomic_load(fp, __ATOMIC_RELAXED, __HIP_MEMORY_SCOPE_AGENT);
                    f2 = __hip_atomic_load(fp, __ATOMIC_RELAXED, __HIP_MEMORY_SCOPE_AGENT);
                }
                if (__ballot(f1 >= need) == ~0ULL) break;
                if (__ballot(f2 >= need) == ~0ULL) break;
                if ((++it & 63) == 0) {
                    int abv = __hip_atomic_load(abortp, __ATOMIC_RELAXED,
                                                __HIP_MEMORY_SCOPE_AGENT);
                    if (abv) { ab = 1; break; }
                    if (it > (1 << 19)) {
                        if (lane == 0)
                            __hip_atomic_store(abortp, 1, __ATOMIC_RELAXED,
                                               __HIP_MEMORY_SCOPE_AGENT);
                        ab = 1; break;
                    }
                }
            }
            if (ab) break;
            // h_{t-1}: 4 independent loads back-to-back (one round-trip)
            const float* hsrc = hbuf + ((size_t)((t - 1) & 1) * BB + myb) * HH;
            const float v0 = __hip_atomic_load(hsrc + lane,       __ATOMIC_RELAXED, __HIP_MEMORY_SCOPE_AGENT);
            const float v1 = __hip_atomic_load(hsrc + lane + 64,  __ATOMIC_RELAXED, __HIP_MEMORY_SCOPE_AGENT);
            const float v2 = __hip_atomic_load(hsrc + lane + 128, __ATOMIC_RELAXED, __HIP_MEMORY_SCOPE_AGENT);
            const float v3 = __hip_atomic_load(hsrc + lane + 192, __ATOMIC_RELAXED, __HIP_MEMORY_SCOPE_AGENT);
            zw[II + lane]       = v0;
            zw[II + lane + 64]  = v1;
            zw[II + lane + 128] = v2;
            zw[II + lane + 192] = v3;
        }

        // ---- h-dot (rows 128..383); broadcast LDS reads, no cross-lane reduce
#pragma unroll
        for (int k = 32; k < 96; ++k) {
            const float4 zv = *(const float4*)(zw + 4 * k);
            acc[k & 3] += zv.x * wr[k].x + zv.y * wr[k].y
                        + zv.z * wr[k].z + zv.w * wr[k].w;
        }
        float s = (acc[0] + acc[1]) + (acc[2] + acc[3]) + bia_reg;

        // ---- gates via shuffles (lane j holds i; j+16 f; j+32 g; j+48 o)
        const float sf = __shfl(s, j + 16);
        const float sg = __shfl(s, j + 32);
        const float so = __shfl(s, j + 48);
        if (lane < 16) {
            const float iv = sigm(s);
            const float fv = sigm(sf);
            const float gv = ftanh(sg);
            const float ov = sigm(so);
            creg = fv * creg + iv * gv;
            const float hv = ov * ftanh(creg);
            __hip_atomic_store(
                hbuf + ((size_t)(t & 1) * BB + myb) * HH + p * 16 + j,
                hv, __ATOMIC_RELAXED, __HIP_MEMORY_SCOPE_AGENT);
        }
        // drain this wave's h stores (x-load long since landed), publish flag
        asm volatile("s_waitcnt vmcnt(0)" ::: "memory");
        if (lane == 0)
            __hip_atomic_store(&flags[blockIdx.x * 16 + w * 4], t,
                               __ATOMIC_RELAXED, __HIP_MEMORY_SCOPE_AGENT);

        // stage x_{t+1} into the strip (regs already drained)
        if (t < TT && lane < 32)
            *(float4*)(zw + 4 * lane) = xv;
    }
}

extern "C" __global__ void __launch_bounds__(256) lstm_out(
    const float* __restrict__ wsf, const float* __restrict__ dw,
    const float* __restrict__ db, float* __restrict__ out)
{
    __shared__ float hs[256];
    __shared__ float red[256];
    const int b = blockIdx.x;
    const int tid = threadIdx.x;
    const float* h0 = wsf + WS_HBUF_F;   // parity 0 holds h_{1024}
    hs[tid] = h0[(size_t)b * HH + tid];
    __syncthreads();
    const int o = tid & 127, half = tid >> 7;
    const float* wrow = dw + o * HH + half * 128;
    const float* hrow = hs + half * 128;
    float s = 0.f;
#pragma unroll
    for (int k = 0; k < 128; k += 4) {
        const float4 wv = *(const float4*)(wrow + k);
        s += hrow[k] * wv.x + hrow[k + 1] * wv.y + hrow[k + 2] * wv.z + hrow[k + 3] * wv.w;
    }
    red[tid] = s;
    __syncthreads();
    if (tid < 128)
        out[(size_t)b * OO + tid] = red[tid] + red[128 + tid] + db[tid];
}

extern "C" void kernel_launch(void* const* d_in, const int* in_sizes, int n_in,
                              void* d_out, int out_size, void* d_ws, size_t ws_size,
                              hipStream_t stream)
{
    const float* x    = (const float*)d_in[0];
    const float* W    = (const float*)d_in[1];
    const float* U    = (const float*)d_in[2];
    const float* bias = (const float*)d_in[3];
    const float* dw   = (const float*)d_in[4];
    const float* db   = (const float*)d_in[5];
    float* out = (float*)d_out;
    float* ws  = (float*)d_ws;

    // zero flags + abort each call (monotone protocol restarts cleanly per replay)
    hipMemsetAsync(d_ws, 0, WS_CLEAR_B, stream);
    hipLaunchKernelGGL(lstm_scan, dim3(256), dim3(256), 0, stream,
                       x, W, U, bias, ws);
    hipLaunchKernelGGL(lstm_out, dim3(64), dim3(256), 0, stream, ws, dw, db, out);
}

// Round 10
// 5680.722 us; speedup vs baseline: 1.2938x; 1.2938x over previous
//
#include <hip/hip_runtime.h>
#include <math.h>

#define TT 1024
#define BB 64
#define II 128
#define HH 256
#define OO 128
#define ZS 392           // per-wave z strip stride (floats)

// ws layout: flags 64 batches x 8 members x 64B = 32KB @0; abort @int 8192
// (byte 32768); hbuf [2][64][256] floats @float 16384 (byte 65536)
#define WS_ABORT_I 8192
#define WS_HBUF_F 16384
#define WS_CLEAR_B 32772

typedef unsigned long long u64;

__device__ __forceinline__ float rcp(float v) { return __builtin_amdgcn_rcpf(v); }
__device__ __forceinline__ float sigm(float v) { return rcp(1.f + __expf(-v)); }
__device__ __forceinline__ float ftanh(float v) {
    return __builtin_fmaf(-2.f, rcp(__expf(2.f * v) + 1.f), 1.f);
}

// 512 blocks = 64 batches x 8 members. Block owns 32 h-dims of ONE batch.
// Wave w owns dims [32m+8w, +8) with all 4 gates -> gates wave-local.
// Column split over 2 adjacent lanes (192 rows each). No barriers in the loop.
extern "C" __global__ void __launch_bounds__(256, 2) lstm_scan(
    const float* __restrict__ x, const float* __restrict__ W,
    const float* __restrict__ U, const float* __restrict__ bias,
    float* __restrict__ wsf)
{
    __shared__ float z[4 * ZS];           // per-wave private strips

    int*   flags  = (int*)wsf;            // [(b*8+m)*16 + w]
    int*   abortp = ((int*)wsf) + WS_ABORT_I;
    float* hbuf   = wsf + WS_HBUF_F;      // [2][64][256]

    const int tid  = threadIdx.x;
    const int b    = blockIdx.x >> 3;     // batch
    const int m    = blockIdx.x & 7;      // member: dims [32m, 32m+32)
    const int lane = tid & 63;
    const int w    = tid >> 6;            // wave: dims [32m+8w, +8)
    const int d    = lane >> 3;           // dim-in-wave (0..7)
    const int g    = (lane >> 1) & 3;     // gate (0..3)
    const int half = lane & 1;            // row half
    const int dim  = 32 * m + 8 * w + d;  // owned h index (lanes with g==0,half==0)
    const int col  = g * HH + dim;        // gate column in [0,1024)

    // ---- weights in VGPRs: 48 x float4 = 192 floats (fits: cap 256, ~230 used)
    // x rows: half*64 .. +63 ; h rows (U): half*128 .. +127
    float4 wx[16], wh[32];
#pragma unroll
    for (int k = 0; k < 16; ++k) {
        const float* p0 = W + (size_t)(half * 64 + 4 * k) * 1024 + col;
        wx[k].x = p0[0]; wx[k].y = p0[1024]; wx[k].z = p0[2048]; wx[k].w = p0[3072];
    }
#pragma unroll
    for (int k = 0; k < 32; ++k) {
        const float* p0 = U + (size_t)(half * 128 + 4 * k) * 1024 + col;
        wh[k].x = p0[0]; wh[k].y = p0[1024]; wh[k].z = p0[2048]; wh[k].w = p0[3072];
    }
    const float bia = bias[col];
    float creg = 0.f;                     // c-state in lanes with lane&7==0

    float* zw = z + w * ZS;               // strip: [0..127]=x_t, [128..383]=h_{t-1}
    for (int i = lane; i < HH; i += 64) zw[II + i] = 0.f;
    float4 xv = make_float4(0.f, 0.f, 0.f, 0.f);
    if (lane < 32) {
        xv = *(const float4*)(x + (size_t)b * TT * II + 4 * lane);
        *(float4*)(zw + 4 * lane) = xv;
    }
    // strip is wave-private; within-wave LDS ordering handled by compiler waits

    int ab = 0;
    for (int t = 1; t <= TT; ++t) {
        float a0 = 0.f, a1 = 0.f, a2 = 0.f, a3 = 0.f;

        // ---- x-dot (this lane's 64 x rows), h-independent
#pragma unroll
        for (int k = 0; k < 16; ++k) {
            const float4 zv = *(const float4*)(zw + half * 64 + 4 * k);
            const float t0 = zv.x * wx[k].x + zv.y * wx[k].y
                           + zv.z * wx[k].z + zv.w * wx[k].w;
            if ((k & 3) == 0) a0 += t0; else if ((k & 3) == 1) a1 += t0;
            else if ((k & 3) == 2) a2 += t0; else a3 += t0;
        }

        // ---- issue x_{t+1} early (latency hides under poll + h-dot)
        if (t < TT && lane < 32)
            xv = *(const float4*)(x + ((size_t)b * TT + t) * II + 4 * lane);

        // ---- poll the 8 member x 4 wave flags of THIS batch (16 lanes, u64 each)
        if (t > 1) {
            const int need = t - 1;
            const u64* fp = (const u64*)flags
                          + ((size_t)b * 8 + ((lane >> 1) & 7)) * 8 + (half & 1);
            int it = 0;
            for (;;) {
                u64 f1 = 0, f2 = 0;
                if (lane < 16) {
                    f1 = __hip_atomic_load(fp, __ATOMIC_RELAXED, __HIP_MEMORY_SCOPE_AGENT);
                    f2 = __hip_atomic_load(fp, __ATOMIC_RELAXED, __HIP_MEMORY_SCOPE_AGENT);
                }
                const bool ok1 = (lane >= 16) ||
                    ((int)(f1 & 0xffffffffu) >= need && (int)(f1 >> 32) >= need);
                const bool ok2 = (lane >= 16) ||
                    ((int)(f2 & 0xffffffffu) >= need && (int)(f2 >> 32) >= need);
                if (__ballot(ok1) == ~0ULL) break;
                if (__ballot(ok2) == ~0ULL) break;
                if ((++it & 31) == 0) {
                    int abv = __hip_atomic_load(abortp, __ATOMIC_RELAXED,
                                                __HIP_MEMORY_SCOPE_AGENT);
                    if (abv) { ab = 1; break; }
                    if (it > (1 << 19)) {
                        if (lane == 0)
                            __hip_atomic_store(abortp, 1, __ATOMIC_RELAXED,
                                               __HIP_MEMORY_SCOPE_AGENT);
                        ab = 1; break;
                    }
                }
                __builtin_amdgcn_s_sleep(1);   // throttle coherence-point traffic
            }
            if (ab) break;

            // h_{t-1}: 4 independent loads back-to-back (one round trip)
            const float* hsrc = hbuf + ((size_t)((t - 1) & 1) * BB + b) * HH;
            const float v0 = __hip_atomic_load(hsrc + lane,       __ATOMIC_RELAXED, __HIP_MEMORY_SCOPE_AGENT);
            const float v1 = __hip_atomic_load(hsrc + lane + 64,  __ATOMIC_RELAXED, __HIP_MEMORY_SCOPE_AGENT);
            const float v2 = __hip_atomic_load(hsrc + lane + 128, __ATOMIC_RELAXED, __HIP_MEMORY_SCOPE_AGENT);
            const float v3 = __hip_atomic_load(hsrc + lane + 192, __ATOMIC_RELAXED, __HIP_MEMORY_SCOPE_AGENT);
            zw[II + lane]       = v0;
            zw[II + lane + 64]  = v1;
            zw[II + lane + 128] = v2;
            zw[II + lane + 192] = v3;
        }

        // ---- h-dot (this lane's 128 h rows); broadcast LDS reads
#pragma unroll
        for (int k = 0; k < 32; ++k) {
            const float4 zv = *(const float4*)(zw + II + half * 128 + 4 * k);
            const float t0 = zv.x * wh[k].x + zv.y * wh[k].y
                           + zv.z * wh[k].z + zv.w * wh[k].w;
            if ((k & 3) == 0) a0 += t0; else if ((k & 3) == 1) a1 += t0;
            else if ((k & 3) == 2) a2 += t0; else a3 += t0;
        }

        // ---- column reduce (2 lanes) + bias; gates via in-wave shuffles
        float s = (a0 + a1) + (a2 + a3);
        s += __shfl_xor(s, 1);
        s += bia;
        const int base = lane & 56;       // lane of (d, g=0, half=0)
        const float sI = __shfl(s, base);
        const float sF = __shfl(s, base + 2);
        const float sG = __shfl(s, base + 4);
        const float sO = __shfl(s, base + 6);
        if ((lane & 7) == 0) {
            const float iv = sigm(sI);
            const float fv = sigm(sF);
            const float gv = ftanh(sG);
            const float ov = sigm(sO);
            creg = fv * creg + iv * gv;
            const float hv = ov * ftanh(creg);
            __hip_atomic_store(hbuf + ((size_t)(t & 1) * BB + b) * HH + dim,
                               hv, __ATOMIC_RELAXED, __HIP_MEMORY_SCOPE_AGENT);
        }
        // drain this wave's h stores, then publish this wave's flag
        asm volatile("s_waitcnt vmcnt(0)" ::: "memory");
        if (lane == 0)
            __hip_atomic_store(&flags[((size_t)b * 8 + m) * 16 + w], t,
                               __ATOMIC_RELAXED, __HIP_MEMORY_SCOPE_AGENT);

        // stage x_{t+1} (xv already landed: covered by the drain above)
        if (t < TT && lane < 32)
            *(float4*)(zw + 4 * lane) = xv;
    }
}

extern "C" __global__ void __launch_bounds__(256) lstm_out(
    const float* __restrict__ wsf, const float* __restrict__ dw,
    const float* __restrict__ db, float* __restrict__ out)
{
    __shared__ float hs[256];
    __shared__ float red[256];
    const int b = blockIdx.x;
    const int tid = threadIdx.x;
    const float* h0 = wsf + WS_HBUF_F;   // parity 0 holds h_{1024}
    hs[tid] = h0[(size_t)b * HH + tid];
    __syncthreads();
    const int o = tid & 127, half = tid >> 7;
    const float* wrow = dw + o * HH + half * 128;
    const float* hrow = hs + half * 128;
    float s = 0.f;
#pragma unroll
    for (int k = 0; k < 128; k += 4) {
        const float4 wv = *(const float4*)(wrow + k);
        s += hrow[k] * wv.x + hrow[k + 1] * wv.y + hrow[k + 2] * wv.z + hrow[k + 3] * wv.w;
    }
    red[tid] = s;
    __syncthreads();
    if (tid < 128)
        out[(size_t)b * OO + tid] = red[tid] + red[128 + tid] + db[tid];
}

extern "C" void kernel_launch(void* const* d_in, const int* in_sizes, int n_in,
                              void* d_out, int out_size, void* d_ws, size_t ws_size,
                              hipStream_t stream)
{
    const float* x    = (const float*)d_in[0];
    const float* W    = (const float*)d_in[1];
    const float* U    = (const float*)d_in[2];
    const float* bias = (const float*)d_in[3];
    const float* dw   = (const float*)d_in[4];
    const float* db   = (const float*)d_in[5];
    float* out = (float*)d_out;
    float* ws  = (float*)d_ws;

    // zero flags + abort each call (monotone protocol restarts cleanly per replay)
    hipMemsetAsync(d_ws, 0, WS_CLEAR_B, stream);
    hipLaunchKernelGGL(lstm_scan, dim3(512), dim3(256), 0, stream,
                       x, W, U, bias, ws);
    hipLaunchKernelGGL(lstm_out, dim3(64), dim3(256), 0, stream, ws, dw, db, out);
}

// Round 11
// 2112.957 us; speedup vs baseline: 3.4785x; 2.6885x over previous
//
#include <hip/hip_runtime.h>
#include <math.h>

#define TT 1024
#define BB 64
#define II 128
#define HH 256
#define OO 128
#define GPB 16           // blocks (members) per group
#define NCOL 64          // gate-columns per block
#define Z_STRIDE 392     // padded z row stride per batch (floats)
#define PART_BG_STRIDE 68
#define PART_RC_STRIDE 273

// ws layout: abort @int 0; tagged hbuf [2][64][256] u64 @byte 16384 (256KB)
#define WS_HBUF_B 16384
#define WS_CLEAR_B (WS_HBUF_B + 2 * BB * HH * 8)

typedef unsigned long long u64;
typedef unsigned int u32;

__device__ __forceinline__ float rcp(float v) { return __builtin_amdgcn_rcpf(v); }
__device__ __forceinline__ float sigm(float v) { return rcp(1.f + __expf(-v)); }
__device__ __forceinline__ float ftanh(float v) {
    return __builtin_fmaf(-2.f, rcp(__expf(2.f * v) + 1.f), 1.f);
}

extern "C" __global__ void __launch_bounds__(256, 1) lstm_scan(
    const float* __restrict__ x, const float* __restrict__ W,
    const float* __restrict__ U, const float* __restrict__ bias,
    float* __restrict__ wsf)
{
    __shared__ float z[4 * Z_STRIDE];
    __shared__ float part[16 * PART_RC_STRIDE];
    __shared__ int   misc[8];

    int* abortp = (int*)wsf;
    u64* hbuf   = (u64*)((char*)wsf + WS_HBUF_B);   // [2][64][256] tagged

    const int tid  = threadIdx.x;
    const int gid  = blockIdx.x & 15;     // group
    const int p    = blockIdx.x >> 4;     // member: owns h-indices [16p,16p+16)
    const int cg   = tid & 15;            // column group (4 logical cols)
    const int rc   = tid >> 4;            // row group
    const int lane = tid & 63;
    const int w    = tid >> 6;            // wave index == batch slot in group
    const int myb  = 4 * gid + w;         // this wave's batch
    const int j    = lane & 15;

    // ---- weights in VGPRs: wr[rr][i][c] = [W;U][rr*64+rc*4+i][cg*4+c]
    float wr[6][4][4];
    {
        const int c0 = cg * 4;
        const int gcol = (c0 >> 4) * HH + p * 16 + (c0 & 15);
#pragma unroll
        for (int rr = 0; rr < 6; ++rr) {
#pragma unroll
            for (int i = 0; i < 4; ++i) {
                const int r = rr * 64 + rc * 4 + i;
                const float4 wv = (rr < 2)
                    ? *(const float4*)(W + (size_t)r * 1024 + gcol)
                    : *(const float4*)(U + (size_t)(r - II) * 1024 + gcol);
                wr[rr][i][0] = wv.x; wr[rr][i][1] = wv.y;
                wr[rr][i][2] = wv.z; wr[rr][i][3] = wv.w;
            }
        }
    }
    // bias for this thread's reduce column (col = lane, same for all waves)
    const float bia_reg = bias[(lane >> 4) * HH + p * 16 + j];
    float creg = 0.f;                     // c-state: lanes 0..15 of each wave

    for (int idx = tid; idx < 4 * Z_STRIDE; idx += 256) z[idx] = 0.f;
    if (tid < 8) misc[tid] = 0;

    // ---- prologue: x_1 into z
    if (tid < 128) {
        const int b2 = tid >> 5, l2 = tid & 31;
        const float4 xv = *(const float4*)(
            x + ((size_t)(4 * gid + b2) * TT + 0) * II + 4 * l2);
        *(float4*)(z + b2 * Z_STRIDE + 4 * l2) = xv;
    }
    __syncthreads();

    for (int t = 1; t <= TT; ++t) {
        float acc[4][4];
#pragma unroll
        for (int a = 0; a < 4; ++a)
#pragma unroll
            for (int b = 0; b < 4; ++b) acc[a][b] = 0.f;

        // ---- matvec over x rows (rr 0..1): h-independent, before the wait
#pragma unroll
        for (int rr = 0; rr < 2; ++rr) {
#pragma unroll
            for (int bg = 0; bg < 4; ++bg) {
                const float4 zv = *(const float4*)(z + bg * Z_STRIDE + rr * 64 + rc * 4);
#pragma unroll
                for (int c = 0; c < 4; ++c)
                    acc[bg][c] += zv.x * wr[rr][0][c] + zv.y * wr[rr][1][c]
                                + zv.z * wr[rr][2][c] + zv.w * wr[rr][3][c];
            }
        }

        // ---- tagged poll: detect == data. UNCONDITIONAL 4-wide load rounds
        // (predicated reloads serialize atomic loads -> 4 RT/round: r6 bug)
        if (t > 1) {
            const u32 want = (u32)(t - 1);
            const u64* hsrc = hbuf + ((size_t)((t - 1) & 1) * BB + myb) * HH;
            u64 n0, n1, n2, n3;
            int it = 0, ab = 0;
            for (;;) {
                n0 = __hip_atomic_load(hsrc + lane,       __ATOMIC_RELAXED, __HIP_MEMORY_SCOPE_AGENT);
                n1 = __hip_atomic_load(hsrc + lane + 64,  __ATOMIC_RELAXED, __HIP_MEMORY_SCOPE_AGENT);
                n2 = __hip_atomic_load(hsrc + lane + 128, __ATOMIC_RELAXED, __HIP_MEMORY_SCOPE_AGENT);
                n3 = __hip_atomic_load(hsrc + lane + 192, __ATOMIC_RELAXED, __HIP_MEMORY_SCOPE_AGENT);
                const bool ok = ((u32)(n0 >> 32) == want) && ((u32)(n1 >> 32) == want)
                             && ((u32)(n2 >> 32) == want) && ((u32)(n3 >> 32) == want);
                if (__ballot(ok) == ~0ULL) break;
                if ((++it & 63) == 0) {
                    int abv = __hip_atomic_load(abortp, __ATOMIC_RELAXED,
                                                __HIP_MEMORY_SCOPE_AGENT);
                    if (abv) { ab = 1; break; }
                    if (it > (1 << 19)) {
                        if (lane == 0)
                            __hip_atomic_store(abortp, 1, __ATOMIC_RELAXED,
                                               __HIP_MEMORY_SCOPE_AGENT);
                        ab = 1; break;
                    }
                }
            }
            if (ab && lane == 0) misc[w] = 1;
            float* zdst = z + w * Z_STRIDE + II + lane;
            zdst[0]   = __uint_as_float((u32)n0);
            zdst[64]  = __uint_as_float((u32)n1);
            zdst[128] = __uint_as_float((u32)n2);
            zdst[192] = __uint_as_float((u32)n3);
        }
        __syncthreads();                         // (1) all z h-parts written
        if (misc[0] | misc[1] | misc[2] | misc[3]) break;

        // ---- matvec over h rows (rr 2..5)
#pragma unroll
        for (int rr = 2; rr < 6; ++rr) {
#pragma unroll
            for (int bg = 0; bg < 4; ++bg) {
                const float4 zv = *(const float4*)(z + bg * Z_STRIDE + rr * 64 + rc * 4);
#pragma unroll
                for (int c = 0; c < 4; ++c)
                    acc[bg][c] += zv.x * wr[rr][0][c] + zv.y * wr[rr][1][c]
                                + zv.z * wr[rr][2][c] + zv.w * wr[rr][3][c];
            }
        }

        // ---- partials to LDS
#pragma unroll
        for (int bg = 0; bg < 4; ++bg)
#pragma unroll
            for (int c = 0; c < 4; ++c)
                part[rc * PART_RC_STRIDE + bg * PART_BG_STRIDE + cg * 4 + c] = acc[bg][c];
        __syncthreads();                         // (2) partials visible

        // ---- per-wave reduce (batch w, col = lane) + shfl gates + tagged publish
        float s = bia_reg;
#pragma unroll
        for (int r2 = 0; r2 < 16; ++r2)
            s += part[r2 * PART_RC_STRIDE + w * PART_BG_STRIDE + lane];

        const float sf = __shfl(s, j + 16);
        const float sg = __shfl(s, j + 32);
        const float so = __shfl(s, j + 48);
        if (lane < 16) {
            const float iv = sigm(s);
            const float fv = sigm(sf);
            const float gv = ftanh(sg);
            const float ov = sigm(so);
            creg = fv * creg + iv * gv;
            const float hv = ov * ftanh(creg);
            const u64 pk = ((u64)(u32)t << 32) | (u64)__float_as_uint(hv);
            __hip_atomic_store(
                hbuf + ((size_t)(t & 1) * BB + myb) * HH + p * 16 + j,
                pk, __ATOMIC_RELAXED, __HIP_MEMORY_SCOPE_AGENT);
        } else if (lane < 48 && t < TT) {
            // x_{t+1} prefetch for this wave's batch
            const int l2 = lane - 16;
            const float4 xv = *(const float4*)(
                x + ((size_t)myb * TT + t) * II + 4 * l2);
            *(float4*)(z + w * Z_STRIDE + 4 * l2) = xv;
        }
        __syncthreads();                         // (3) x_{t+1} staged; z reusable
    }
}

extern "C" __global__ void __launch_bounds__(256) lstm_out(
    const float* __restrict__ wsf, const float* __restrict__ dw,
    const float* __restrict__ db, float* __restrict__ out)
{
    __shared__ float hs[256];
    __shared__ float red[256];
    const int b = blockIdx.x;
    const int tid = threadIdx.x;
    const u64* h0 = (const u64*)((const char*)wsf + WS_HBUF_B);  // parity 0 = h_1024
    hs[tid] = __uint_as_float((u32)h0[(size_t)b * HH + tid]);
    __syncthreads();
    const int o = tid & 127, half = tid >> 7;
    const float* wrow = dw + o * HH + half * 128;
    const float* hrow = hs + half * 128;
    float s = 0.f;
#pragma unroll
    for (int k = 0; k < 128; k += 4) {
        const float4 wv = *(const float4*)(wrow + k);
        s += hrow[k] * wv.x + hrow[k + 1] * wv.y + hrow[k + 2] * wv.z + hrow[k + 3] * wv.w;
    }
    red[tid] = s;
    __syncthreads();
    if (tid < 128)
        out[(size_t)b * OO + tid] = red[tid] + red[128 + tid] + db[tid];
}

extern "C" void kernel_launch(void* const* d_in, const int* in_sizes, int n_in,
                              void* d_out, int out_size, void* d_ws, size_t ws_size,
                              hipStream_t stream)
{
    const float* x    = (const float*)d_in[0];
    const float* W    = (const float*)d_in[1];
    const float* U    = (const float*)d_in[2];
    const float* bias = (const float*)d_in[3];
    const float* dw   = (const float*)d_in[4];
    const float* db   = (const float*)d_in[5];
    float* out = (float*)d_out;
    float* ws  = (float*)d_ws;

    // zero abort + tagged hbuf each call (tag=0 never matches t>=1 ->
    // no cross-replay staleness)
    hipMemsetAsync(d_ws, 0, WS_CLEAR_B, stream);
    hipLaunchKernelGGL(lstm_scan, dim3(256), dim3(256), 0, stream,
                       x, W, U, bias, ws);
    hipLaunchKernelGGL(lstm_out, dim3(64), dim3(256), 0, stream, ws, dw, db, out);
}